// Round 1
// baseline (1023.803 us; speedup 1.0000x reference)
//
#include <hip/hip_runtime.h>

#define NN 160
#define MAT (NN*NN)            // 25600
#define BCN 1024               // B*C
#define BIG ((size_t)BCN * MAT)
#define PKSZ 12800             // uints per bc in PK layout: 20 k8-groups * 160 * 4
#define ALPHA 0.05f
#define BETA  0.95f

typedef unsigned int u32;
typedef __attribute__((ext_vector_type(8))) short short8;   // 8 bf16 = 4 VGPRs
typedef __attribute__((ext_vector_type(4))) float f32x4;

// pack two fp32 -> bf16 pair (RNE), lo in low 16, hi in high 16
static __device__ __forceinline__ u32 pk2(float lo, float hi) {
    u32 a = __float_as_uint(lo), b = __float_as_uint(hi);
    a += 0x7fffu + ((a >> 16) & 1u);
    b += 0x7fffu + ((b >> 16) & 1u);
    return (a >> 16) | (b & 0xffff0000u);
}

// ---------------------------------------------------------------------------
// prep_sums: sums[v] = 1/(rowsum_v(a)+1), sums[160+v] = 1/(colsum_v(a)+1)
// ---------------------------------------------------------------------------
__global__ __launch_bounds__(256) void prep_sums(const float* __restrict__ a,
                                                 float* __restrict__ sums)
{
    __shared__ float rbuf[256], cbuf[256];
    int b = blockIdx.x, t = threadIdx.x;
    float r = 0.f, c = 0.f;
    if (t < NN) { r = a[b*NN + t]; c = a[t*NN + b]; }
    rbuf[t] = r; cbuf[t] = c;
    __syncthreads();
    for (int s = 128; s > 0; s >>= 1) {
        if (t < s) { rbuf[t] += rbuf[t+s]; cbuf[t] += cbuf[t+s]; }
        __syncthreads();
    }
    if (t == 0) {
        sums[b]      = 1.f / (rbuf[0] + 1.f);
        sums[NN + b] = 1.f / (cbuf[0] + 1.f);
    }
}

// ---------------------------------------------------------------------------
// prep_norm: A1f[v][w] = (a[v][w]+d)*rs[v]   (rownorm(a+I))
//            A2f[v][w] = (a[w][v]+d)*cs[v]   (rownorm(a^T+I))
// ---------------------------------------------------------------------------
__global__ __launch_bounds__(256) void prep_norm(
    const float* __restrict__ a, const float* __restrict__ sums,
    float* __restrict__ A1f, float* __restrict__ A2f)
{
    int i = blockIdx.x * 256 + threadIdx.x;   // 25600 exact (100 blocks)
    int v = i / NN, w = i % NN;
    float d = (v == w) ? 1.f : 0.f;
    A1f[i] = (a[v*NN + w] + d) * sums[v];
    A2f[i] = (a[w*NN + v] + d) * sums[NN + v];
}

// ---------------------------------------------------------------------------
// prep_mm: Ab = alpha*I + alpha*beta*A + beta^2 * A@A   for A1f and A2f
// ---------------------------------------------------------------------------
__global__ __launch_bounds__(256) void prep_mm(
    const float* __restrict__ A1f, const float* __restrict__ A2f,
    float* __restrict__ Ab1f, float* __restrict__ Ab2f)
{
    int idx = blockIdx.x * 256 + threadIdx.x;   // 51200 exact (200 blocks)
    int mtx = idx / MAT;
    int i = idx % MAT;
    int v = i / NN, l = i % NN;
    const float* A = mtx ? A2f : A1f;
    float s = 0.f;
    for (int w = 0; w < NN; ++w) s = fmaf(A[v*NN + w], A[w*NN + l], s);
    float d = (v == l) ? ALPHA : 0.f;
    float o = d + ALPHA*BETA*A[i] + BETA*BETA*s;
    (mtx ? Ab2f : Ab1f)[i] = o;
}

// ---------------------------------------------------------------------------
// prep_pk: pack 3 shared A-operand matrices into PK layout.
// G1 = At1@x + At2@x = (At1+At2)@x and G2 = (Ab1+Ab2)@x, so sum BEFORE pack:
// mtx 0: At12 = beta*(A1+A2) + 2*alpha*I ; 1: Ah12 = Ab1+Ab2 ; 2: a
// pk[k8][v][j] = pack(M[v][8k8+2j], M[v][8k8+2j+1])
// ---------------------------------------------------------------------------
__global__ __launch_bounds__(256) void prep_pk(
    const float* __restrict__ a, const float* __restrict__ A1f,
    const float* __restrict__ A2f, const float* __restrict__ Ab1f,
    const float* __restrict__ Ab2f,
    u32* __restrict__ At12pk, u32* __restrict__ Ah12pk, u32* __restrict__ apk)
{
    int idx = blockIdx.x * 256 + threadIdx.x;
    if (idx >= 3 * 3200) return;
    int mtx = idx / 3200;
    int r = idx % 3200;
    int k8 = r / 160, v = r % 160;
    u32 o[4];
    #pragma unroll
    for (int j = 0; j < 4; ++j) {
        int w0 = k8*8 + 2*j;
        float f0, f1;
        if (mtx == 0) {
            f0 = BETA*(A1f[v*NN + w0]     + A2f[v*NN + w0])     + ((v == w0)   ? 2.f*ALPHA : 0.f);
            f1 = BETA*(A1f[v*NN + w0 + 1] + A2f[v*NN + w0 + 1]) + ((v == w0+1) ? 2.f*ALPHA : 0.f);
        } else if (mtx == 1) {
            f0 = Ab1f[v*NN + w0]     + Ab2f[v*NN + w0];
            f1 = Ab1f[v*NN + w0 + 1] + Ab2f[v*NN + w0 + 1];
        } else {
            f0 = a[v*NN + w0];
            f1 = a[v*NN + w0 + 1];
        }
        o[j] = pk2(f0, f1);
    }
    u32* dst = (mtx == 0) ? At12pk : (mtx == 1) ? Ah12pk : apk;
    *(uint4*)&dst[(k8*160 + v)*4] = make_uint4(o[0], o[1], o[2], o[3]);
}

// ---------------------------------------------------------------------------
// cvt_x_pk: x fp32 [bc][v][l] -> PK (contraction dim = v):
//   xpk[bc][k8][l][j] = pack(x[8k8+2j][l], x[8k8+2j+1][l])
// one thread per uint4 (one (bc,k8,l))
// ---------------------------------------------------------------------------
__global__ __launch_bounds__(256) void cvt_x_pk(const float* __restrict__ x,
                                                u32* __restrict__ xpk)
{
    int idx = blockIdx.x * 256 + threadIdx.x;   // 3,276,800 (12800 blocks)
    int l  = idx % NN;
    int k8 = (idx / NN) % 20;
    int bc = idx / 3200;
    const float* xb = x + (size_t)bc * MAT + (size_t)(k8*8) * NN + l;
    u32 o[4];
    #pragma unroll
    for (int j = 0; j < 4; ++j)
        o[j] = pk2(xb[(2*j)*NN], xb[(2*j+1)*NN]);
    *(uint4*)&xpk[(size_t)bc * PKSZ + (size_t)(k8*160 + l)*4] =
        make_uint4(o[0], o[1], o[2], o[3]);
}

// ---------------------------------------------------------------------------
// bgemm16: per-block one bc. C[v][l] = sum_w A(v,w) * Q(w,l), MFMA 16x16x32 bf16.
// A, Q in PK layout. astride=0 for shared A, PKSZ for per-bc A.
// Cf: fp32 output (nullable); cacc: C += result; Cpk: PK output of raw result.
// 4 waves, each an 80x80 quadrant (5x5 tiles of 16x16), K-chunks of 32.
// ---------------------------------------------------------------------------
__global__ __launch_bounds__(256, 2) void bgemm16(
    const u32* __restrict__ Apk, long astride,
    const u32* __restrict__ Qpk,
    float* __restrict__ Cf, int cacc,
    u32* __restrict__ Cpk)
{
    __shared__ u32 As[2560];   // 4 k8-groups x 160 rows x 4 uints = 10240 B
    __shared__ u32 Bs[2560];
    int bc = blockIdx.x;
    int t = threadIdx.x;
    int lane = t & 63, w = t >> 6;
    int q = lane >> 4, ll = lane & 15;
    int v0w = (w >> 1) * 80, l0w = (w & 1) * 80;
    const u32* Ab = Apk + (size_t)bc * (size_t)astride;
    const u32* Qb = Qpk + (size_t)bc * PKSZ;

    f32x4 acc[5][5];
    #pragma unroll
    for (int rt = 0; rt < 5; ++rt)
        #pragma unroll
        for (int ct = 0; ct < 5; ++ct)
            acc[rt][ct] = (f32x4){0.f, 0.f, 0.f, 0.f};

    for (int c = 0; c < 5; ++c) {       // 5 K-chunks of 32
        __syncthreads();
        for (int i = t; i < 640; i += 256) {
            *(uint4*)&As[i*4] = *(const uint4*)&Ab[(size_t)c*2560 + i*4];
            *(uint4*)&Bs[i*4] = *(const uint4*)&Qb[(size_t)c*2560 + i*4];
        }
        __syncthreads();
        short8 af[5], bf[5];
        #pragma unroll
        for (int rt = 0; rt < 5; ++rt)
            af[rt] = *(const short8*)&As[(q*160 + v0w + rt*16 + ll)*4];
        #pragma unroll
        for (int ct = 0; ct < 5; ++ct)
            bf[ct] = *(const short8*)&Bs[(q*160 + l0w + ct*16 + ll)*4];
        #pragma unroll
        for (int rt = 0; rt < 5; ++rt)
            #pragma unroll
            for (int ct = 0; ct < 5; ++ct)
                acc[rt][ct] = __builtin_amdgcn_mfma_f32_16x16x32_bf16(
                    af[rt], bf[ct], acc[rt][ct], 0, 0, 0);
    }

    // epilogue: C/D layout col=lane&15, row=(lane>>4)*4+reg  [m89-verified]
    float* Cb = Cf  ? Cf  + (size_t)bc * MAT  : (float*)0;
    u32*   Pb = Cpk ? Cpk + (size_t)bc * PKSZ : (u32*)0;
    #pragma unroll
    for (int rt = 0; rt < 5; ++rt) {
        int vb = v0w + rt*16 + q*4;       // first of 4 consecutive rows
        #pragma unroll
        for (int ct = 0; ct < 5; ++ct) {
            int l = l0w + ct*16 + ll;
            f32x4 o = acc[rt][ct];
            if (Pb) {                     // PK of raw GEMM result
                int k8 = vb >> 3, j = (vb >> 1) & 3;
                size_t pa = (size_t)(k8*160 + l)*4 + j;
                Pb[pa]     = pk2(o.x, o.y);
                Pb[pa + 1] = pk2(o.z, o.w);
            }
            if (Cb) {
                size_t base = (size_t)vb * NN + l;
                if (cacc) {
                    o.x += Cb[base];
                    o.y += Cb[base + NN];
                    o.z += Cb[base + 2*NN];
                    o.w += Cb[base + 3*NN];
                }
                Cb[base]        = o.x;
                Cb[base + NN]   = o.y;
                Cb[base + 2*NN] = o.z;
                Cb[base + 3*NN] = o.w;
            }
        }
    }
}

// ---------------------------------------------------------------------------
// chanmix: thread handles v-pair (2v0, 2v0+1) at (b, l) for a HALF of the 32
// output channels (oh selects o-range [16*oh, 16*oh+16)).  64 fp32 accumulators
// per thread -> fits VGPRs, no scratch spill (the 128-acc version spilled:
// VGPR_Count=72 with 128 live accumulators, +100MB scratch WRITE_SIZE).
// W loads widened to float4 (1 load : 8 FMA ratio).
// embed emitted in PK layout (contraction dim = node v), pool in fp32.
// ---------------------------------------------------------------------------
__global__ __launch_bounds__(256) void chanmix(
    const float* __restrict__ x, const float* __restrict__ g1, const float* __restrict__ g2,
    const float* __restrict__ We, const float* __restrict__ be,
    const float* __restrict__ Wp, const float* __restrict__ bp,
    u32* __restrict__ embed_pk, float* __restrict__ pool)
{
    int idx = blockIdx.x * 256 + threadIdx.x;   // 819,200 (3200 blocks)
    int l  = idx % NN;
    int v0 = (idx / NN) % 80;
    int oh = (idx / (NN * 80)) & 1;             // wave-uniform (12800 % 64 == 0)
    int b  = idx / (NN * 160);
    int ob = oh * 16;
    size_t base0 = (size_t)b * (32*MAT) + (size_t)(2*v0) * NN + l;
    size_t base1 = base0 + NN;
    const size_t coff = MAT;

    float e0[16], e1[16], p0[16], p1[16];
    #pragma unroll
    for (int o = 0; o < 16; ++o) {
        float b2e = 2.f * be[ob + o], b2p = 2.f * bp[ob + o];
        e0[o] = b2e; e1[o] = b2e; p0[o] = b2p; p1[o] = b2p;
    }
    #pragma unroll 1
    for (int k = 0; k < 3; ++k) {
        const float* s = (k == 0) ? x : ((k == 1) ? g1 : g2);
        float sc = (k == 0) ? 2.f : 1.f;
        #pragma unroll 1
        for (int c4 = 0; c4 < 8; ++c4) {        // 32 channels in chunks of 4
            float h0[4], h1[4];
            #pragma unroll
            for (int j = 0; j < 4; ++j) {
                h0[j] = s[base0 + (size_t)(c4*4 + j)*coff] * sc;
                h1[j] = s[base1 + (size_t)(c4*4 + j)*coff] * sc;
            }
            #pragma unroll
            for (int o = 0; o < 16; ++o) {
                f32x4 we = *(const f32x4*)&We[(ob + o)*96 + k*32 + c4*4];
                f32x4 wp = *(const f32x4*)&Wp[(ob + o)*96 + k*32 + c4*4];
                #pragma unroll
                for (int j = 0; j < 4; ++j) {
                    e0[o] = fmaf(we[j], h0[j], e0[o]);
                    e1[o] = fmaf(we[j], h1[j], e1[o]);
                    p0[o] = fmaf(wp[j], h0[j], p0[o]);
                    p1[o] = fmaf(wp[j], h1[j], p1[o]);
                }
            }
        }
    }
    int k8 = v0 >> 2, j = v0 & 3;
    #pragma unroll
    for (int o = 0; o < 16; ++o) {
        size_t bo = (size_t)(b*32 + ob + o);
        pool[bo*MAT + (size_t)(2*v0)*NN + l]     = p0[o];
        pool[bo*MAT + (size_t)(2*v0+1)*NN + l]   = p1[o];
        embed_pk[bo*PKSZ + (size_t)(k8*160 + l)*4 + j] = pk2(e0[o], e1[o]);
    }
}

// ---------------------------------------------------------------------------
// softmax over node dim (read-only input); emits srpk = PK over node-row pairs
// (B-operand of a@s and A-operand of s^T@embed) AND scpk = PK over column
// pairs (A-operand of s@M, was the separate tpack kernel).  Column-pair values
// come from the neighbor lane via shfl (lane parity == l parity since 160 and
// 64 are even; pair never straddles a wave).  fp32 s is never stored.
// ---------------------------------------------------------------------------
__global__ __launch_bounds__(256) void softmax_n(const float* __restrict__ p,
                                                 u32* __restrict__ srpk,
                                                 u32* __restrict__ scpk)
{
    int idx = blockIdx.x * 256 + threadIdx.x;   // 163,840 columns
    int l  = idx % NN;
    int bo = idx / NN;
    const float* col = p + (size_t)bo * MAT + l;
    float m = -1e30f, s = 0.f;
    for (int n = 0; n < NN; ++n) {
        float v  = col[(size_t)n * NN];
        float mn = fmaxf(m, v);
        s = s * __expf(m - mn) + __expf(v - mn);
        m = mn;
    }
    float inv = 1.f / s;
    u32* sp = srpk + (size_t)bo * PKSZ;
    u32* cp = scpk + (size_t)bo * PKSZ;
    int k8c = l >> 3, jc = (l >> 1) & 3;
    bool wlane = ((l & 1) == 0);
    for (int k2 = 0; k2 < 80; ++k2) {
        float s0 = __expf(col[(size_t)(2*k2)   * NN] - m) * inv;
        float s1 = __expf(col[(size_t)(2*k2+1) * NN] - m) * inv;
        sp[(size_t)((k2 >> 2)*160 + l)*4 + (k2 & 3)] = pk2(s0, s1);
        float t0 = __shfl_down(s0, 1);
        float t1 = __shfl_down(s1, 1);
        if (wlane) {
            cp[(size_t)(k8c*160 + 2*k2)*4 + jc]     = pk2(s0, t0);
            cp[(size_t)(k8c*160 + 2*k2 + 1)*4 + jc] = pk2(s1, t1);
        }
    }
}

// ---------------------------------------------------------------------------
extern "C" void kernel_launch(void* const* d_in, const int* in_sizes, int n_in,
                              void* d_out, int out_size, void* d_ws, size_t ws_size,
                              hipStream_t stream)
{
    const float* x  = (const float*)d_in[0];
    const float* a  = (const float*)d_in[1];
    const float* We = (const float*)d_in[2];
    const float* be = (const float*)d_in[3];
    const float* Wp = (const float*)d_in[4];
    const float* bp = (const float*)d_in[5];

    float* part0 = (float*)d_out;          // pool -> x_new
    float* part1 = part0 + BIG;            // G2 -> a_new

    char* ws = (char*)d_ws;
    // persistent small PK mats: 3 x 51200 B
    u32* At12pk = (u32*)(ws + 0);
    u32* Ah12pk = (u32*)(ws + 51200);
    u32* apk    = (u32*)(ws + 102400);
    // big regions
    float* B1      = (float*)(ws + 256000);                 // 104,857,600 B: G1 -> srpk+scpk
    u32*   R3      = (u32*)  (ws + 256000 + 104857600);     //  52,428,800 B: x_pk -> embed_pk
    u32*   R4      = (u32*)  (ws + 256000 + 157286400);     //  52,428,800 B: M_pk
    // total: 209,971,200 B
    // prep-phase temps live inside B1 (dead before first bgemm writes B1)
    float* sums = B1;                       // 320 floats
    float* A1f  = (float*)((char*)B1 + 1536);
    float* A2f  = A1f + MAT;
    float* Ab1f = A2f + MAT;
    float* Ab2f = Ab1f + MAT;
    u32* x_pk     = R3;
    u32* embed_pk = R3;
    u32* srpk = (u32*)B1;
    u32* scpk = (u32*)((char*)B1 + 52428800);
    u32* M_pk = R4;

    // ---- prep (tiny) ----
    prep_sums<<<160, 256, 0, stream>>>(a, sums);
    prep_norm<<<100, 256, 0, stream>>>(a, sums, A1f, A2f);
    prep_mm  <<<200, 256, 0, stream>>>(A1f, A2f, Ab1f, Ab2f);
    prep_pk  <<<38, 256, 0, stream>>>(a, A1f, A2f, Ab1f, Ab2f,
                                      At12pk, Ah12pk, apk);
    cvt_x_pk <<<12800, 256, 0, stream>>>(x, x_pk);

    // ---- hop GEMMs (merged: G1 = (At1+At2)@x, G2 = (Ab1+Ab2)@x) ----
    bgemm16<<<BCN, 256, 0, stream>>>(At12pk, 0, x_pk, B1,    0, (u32*)0);  // G1
    bgemm16<<<BCN, 256, 0, stream>>>(Ah12pk, 0, x_pk, part1, 0, (u32*)0);  // G2

    // ---- channel mix + softmax(+packs fused) ----
    chanmix<<<3200, 256, 0, stream>>>(x, B1, part1, We, be, Wp, bp, embed_pk, part0);
    softmax_n<<<640, 256, 0, stream>>>(part0, srpk, scpk);

    // ---- output GEMMs ----
    // M = a@s (PK-only output)
    bgemm16<<<BCN, 256, 0, stream>>>(apk, 0, srpk, (float*)0, 0, M_pk);
    // x_new = s^T @ embed
    bgemm16<<<BCN, 256, 0, stream>>>(srpk, (long)PKSZ, embed_pk, part0, 0, (u32*)0);
    // a_new = s @ M
    bgemm16<<<BCN, 256, 0, stream>>>(scpk, (long)PKSZ, M_pk, part1, 0, (u32*)0);
}

// Round 2
// 880.398 us; speedup vs baseline: 1.1629x; 1.1629x over previous
//
#include <hip/hip_runtime.h>

#define NN 160
#define MAT (NN*NN)            // 25600
#define BCN 1024               // B*C
#define BIG ((size_t)BCN * MAT)
#define PKSZ 12800             // uints per bc in PK layout: 20 k8-groups * 160 * 4
#define ALPHA 0.05f
#define BETA  0.95f

typedef unsigned int u32;
typedef __attribute__((ext_vector_type(8))) short short8;   // 8 bf16 = 4 VGPRs
typedef __attribute__((ext_vector_type(4))) float f32x4;

// pack two fp32 -> bf16 pair (RNE), lo in low 16, hi in high 16
static __device__ __forceinline__ u32 pk2(float lo, float hi) {
    u32 a = __float_as_uint(lo), b = __float_as_uint(hi);
    a += 0x7fffu + ((a >> 16) & 1u);
    b += 0x7fffu + ((b >> 16) & 1u);
    return (a >> 16) | (b & 0xffff0000u);
}

// ---------------------------------------------------------------------------
// prep_sums: sums[v] = 1/(rowsum_v(a)+1), sums[160+v] = 1/(colsum_v(a)+1)
// ---------------------------------------------------------------------------
__global__ __launch_bounds__(256) void prep_sums(const float* __restrict__ a,
                                                 float* __restrict__ sums)
{
    __shared__ float rbuf[256], cbuf[256];
    int b = blockIdx.x, t = threadIdx.x;
    float r = 0.f, c = 0.f;
    if (t < NN) { r = a[b*NN + t]; c = a[t*NN + b]; }
    rbuf[t] = r; cbuf[t] = c;
    __syncthreads();
    for (int s = 128; s > 0; s >>= 1) {
        if (t < s) { rbuf[t] += rbuf[t+s]; cbuf[t] += cbuf[t+s]; }
        __syncthreads();
    }
    if (t == 0) {
        sums[b]      = 1.f / (rbuf[0] + 1.f);
        sums[NN + b] = 1.f / (cbuf[0] + 1.f);
    }
}

// ---------------------------------------------------------------------------
// prep_norm: A1f[v][w] = (a[v][w]+d)*rs[v]   (rownorm(a+I))
//            A2f[v][w] = (a[w][v]+d)*cs[v]   (rownorm(a^T+I))
// ---------------------------------------------------------------------------
__global__ __launch_bounds__(256) void prep_norm(
    const float* __restrict__ a, const float* __restrict__ sums,
    float* __restrict__ A1f, float* __restrict__ A2f)
{
    int i = blockIdx.x * 256 + threadIdx.x;   // 25600 exact (100 blocks)
    int v = i / NN, w = i % NN;
    float d = (v == w) ? 1.f : 0.f;
    A1f[i] = (a[v*NN + w] + d) * sums[v];
    A2f[i] = (a[w*NN + v] + d) * sums[NN + v];
}

// ---------------------------------------------------------------------------
// prep_mm: Ab = alpha*I + alpha*beta*A + beta^2 * A@A   for A1f and A2f
// ---------------------------------------------------------------------------
__global__ __launch_bounds__(256) void prep_mm(
    const float* __restrict__ A1f, const float* __restrict__ A2f,
    float* __restrict__ Ab1f, float* __restrict__ Ab2f)
{
    int idx = blockIdx.x * 256 + threadIdx.x;   // 51200 exact (200 blocks)
    int mtx = idx / MAT;
    int i = idx % MAT;
    int v = i / NN, l = i % NN;
    const float* A = mtx ? A2f : A1f;
    float s = 0.f;
    for (int w = 0; w < NN; ++w) s = fmaf(A[v*NN + w], A[w*NN + l], s);
    float d = (v == l) ? ALPHA : 0.f;
    float o = d + ALPHA*BETA*A[i] + BETA*BETA*s;
    (mtx ? Ab2f : Ab1f)[i] = o;
}

// ---------------------------------------------------------------------------
// prep_pk: pack 3 shared A-operand matrices into PK layout.
// G1 = At1@x + At2@x = (At1+At2)@x and G2 = (Ab1+Ab2)@x, so sum BEFORE pack:
// mtx 0: At12 = beta*(A1+A2) + 2*alpha*I ; 1: Ah12 = Ab1+Ab2 ; 2: a
// pk[k8][v][j] = pack(M[v][8k8+2j], M[v][8k8+2j+1])
// ---------------------------------------------------------------------------
__global__ __launch_bounds__(256) void prep_pk(
    const float* __restrict__ a, const float* __restrict__ A1f,
    const float* __restrict__ A2f, const float* __restrict__ Ab1f,
    const float* __restrict__ Ab2f,
    u32* __restrict__ At12pk, u32* __restrict__ Ah12pk, u32* __restrict__ apk)
{
    int idx = blockIdx.x * 256 + threadIdx.x;
    if (idx >= 3 * 3200) return;
    int mtx = idx / 3200;
    int r = idx % 3200;
    int k8 = r / 160, v = r % 160;
    u32 o[4];
    #pragma unroll
    for (int j = 0; j < 4; ++j) {
        int w0 = k8*8 + 2*j;
        float f0, f1;
        if (mtx == 0) {
            f0 = BETA*(A1f[v*NN + w0]     + A2f[v*NN + w0])     + ((v == w0)   ? 2.f*ALPHA : 0.f);
            f1 = BETA*(A1f[v*NN + w0 + 1] + A2f[v*NN + w0 + 1]) + ((v == w0+1) ? 2.f*ALPHA : 0.f);
        } else if (mtx == 1) {
            f0 = Ab1f[v*NN + w0]     + Ab2f[v*NN + w0];
            f1 = Ab1f[v*NN + w0 + 1] + Ab2f[v*NN + w0 + 1];
        } else {
            f0 = a[v*NN + w0];
            f1 = a[v*NN + w0 + 1];
        }
        o[j] = pk2(f0, f1);
    }
    u32* dst = (mtx == 0) ? At12pk : (mtx == 1) ? Ah12pk : apk;
    *(uint4*)&dst[(k8*160 + v)*4] = make_uint4(o[0], o[1], o[2], o[3]);
}

// ---------------------------------------------------------------------------
// cvt_x_pk: x fp32 [bc][v][l] -> PK (contraction dim = v):
//   xpk[bc][k8][l][j] = pack(x[8k8+2j][l], x[8k8+2j+1][l])
// one thread per uint4 (one (bc,k8,l))
// ---------------------------------------------------------------------------
__global__ __launch_bounds__(256) void cvt_x_pk(const float* __restrict__ x,
                                                u32* __restrict__ xpk)
{
    int idx = blockIdx.x * 256 + threadIdx.x;   // 3,276,800 (12800 blocks)
    int l  = idx % NN;
    int k8 = (idx / NN) % 20;
    int bc = idx / 3200;
    const float* xb = x + (size_t)bc * MAT + (size_t)(k8*8) * NN + l;
    u32 o[4];
    #pragma unroll
    for (int j = 0; j < 4; ++j)
        o[j] = pk2(xb[(2*j)*NN], xb[(2*j+1)*NN]);
    *(uint4*)&xpk[(size_t)bc * PKSZ + (size_t)(k8*160 + l)*4] =
        make_uint4(o[0], o[1], o[2], o[3]);
}

// ---------------------------------------------------------------------------
// bgemm16: per-block one bc. C[v][l] = sum_w A(v,w) * Q(w,l), MFMA 16x16x32 bf16.
// A, Q in PK layout. astride=0 for shared A, PKSZ for per-bc A.
// Cf: fp32 output (nullable); cacc: C += result; Cpk: PK output of raw result.
// 4 waves, each an 80x80 quadrant (5x5 tiles of 16x16), K-chunks of 32.
// ---------------------------------------------------------------------------
__global__ __launch_bounds__(256, 2) void bgemm16(
    const u32* __restrict__ Apk, long astride,
    const u32* __restrict__ Qpk,
    float* __restrict__ Cf, int cacc,
    u32* __restrict__ Cpk)
{
    __shared__ u32 As[2560];   // 4 k8-groups x 160 rows x 4 uints = 10240 B
    __shared__ u32 Bs[2560];
    int bc = blockIdx.x;
    int t = threadIdx.x;
    int lane = t & 63, w = t >> 6;
    int q = lane >> 4, ll = lane & 15;
    int v0w = (w >> 1) * 80, l0w = (w & 1) * 80;
    const u32* Ab = Apk + (size_t)bc * (size_t)astride;
    const u32* Qb = Qpk + (size_t)bc * PKSZ;

    f32x4 acc[5][5];
    #pragma unroll
    for (int rt = 0; rt < 5; ++rt)
        #pragma unroll
        for (int ct = 0; ct < 5; ++ct)
            acc[rt][ct] = (f32x4){0.f, 0.f, 0.f, 0.f};

    for (int c = 0; c < 5; ++c) {       // 5 K-chunks of 32
        __syncthreads();
        for (int i = t; i < 640; i += 256) {
            *(uint4*)&As[i*4] = *(const uint4*)&Ab[(size_t)c*2560 + i*4];
            *(uint4*)&Bs[i*4] = *(const uint4*)&Qb[(size_t)c*2560 + i*4];
        }
        __syncthreads();
        short8 af[5], bf[5];
        #pragma unroll
        for (int rt = 0; rt < 5; ++rt)
            af[rt] = *(const short8*)&As[(q*160 + v0w + rt*16 + ll)*4];
        #pragma unroll
        for (int ct = 0; ct < 5; ++ct)
            bf[ct] = *(const short8*)&Bs[(q*160 + l0w + ct*16 + ll)*4];
        #pragma unroll
        for (int rt = 0; rt < 5; ++rt)
            #pragma unroll
            for (int ct = 0; ct < 5; ++ct)
                acc[rt][ct] = __builtin_amdgcn_mfma_f32_16x16x32_bf16(
                    af[rt], bf[ct], acc[rt][ct], 0, 0, 0);
    }

    // epilogue: C/D layout col=lane&15, row=(lane>>4)*4+reg  [m89-verified]
    float* Cb = Cf  ? Cf  + (size_t)bc * MAT  : (float*)0;
    u32*   Pb = Cpk ? Cpk + (size_t)bc * PKSZ : (u32*)0;
    #pragma unroll
    for (int rt = 0; rt < 5; ++rt) {
        int vb = v0w + rt*16 + q*4;       // first of 4 consecutive rows
        #pragma unroll
        for (int ct = 0; ct < 5; ++ct) {
            int l = l0w + ct*16 + ll;
            f32x4 o = acc[rt][ct];
            if (Pb) {                     // PK of raw GEMM result
                int k8 = vb >> 3, j = (vb >> 1) & 3;
                size_t pa = (size_t)(k8*160 + l)*4 + j;
                Pb[pa]     = pk2(o.x, o.y);
                Pb[pa + 1] = pk2(o.z, o.w);
            }
            if (Cb) {
                size_t base = (size_t)vb * NN + l;
                if (cacc) {
                    o.x += Cb[base];
                    o.y += Cb[base + NN];
                    o.z += Cb[base + 2*NN];
                    o.w += Cb[base + 3*NN];
                }
                Cb[base]        = o.x;
                Cb[base + NN]   = o.y;
                Cb[base + 2*NN] = o.z;
                Cb[base + 3*NN] = o.w;
            }
        }
    }
}

// ---------------------------------------------------------------------------
// chanmix v3: ONE v-row per thread, ALL 64 output channels (32 e + 32 p).
//  - W indices depend only on loop constants -> provably wave-uniform ->
//    compiler serves We/Wp via s_load into SGPRs (round-0 had SGPR=96 for
//    this reason; round-1's oh-split killed it, SGPR dropped to 32 and W
//    went to per-lane vector loads: the 2.3x regression).
//  - 64 accumulators + 4 h regs fits VGPRs (round-0's 128 accs spilled).
//  - lane pairing: idx = (((b*80+v0)*160)+l)*2 + (v&1), so lane parity ==
//    v parity and the embed_pk v-pair comes from __shfl_down(e,1) (pair
//    never straddles a wave; same trick verified in softmax_n).
//  - each x/g1/g2 element is read by exactly ONE thread (no read doubling).
// ---------------------------------------------------------------------------
__global__ __launch_bounds__(256, 4) void chanmix(
    const float* __restrict__ x, const float* __restrict__ g1, const float* __restrict__ g2,
    const float* __restrict__ We, const float* __restrict__ be,
    const float* __restrict__ Wp, const float* __restrict__ bp,
    u32* __restrict__ embed_pk, float* __restrict__ pool)
{
    int idx = blockIdx.x * 256 + threadIdx.x;   // 819,200 (3200 blocks)
    int vbit = idx & 1;
    int t2 = idx >> 1;
    int l  = t2 % NN;
    int v0 = (t2 / NN) % 80;
    int b  = t2 / (NN * 80);
    int v  = 2*v0 + vbit;
    size_t base = (size_t)b * (32*MAT) + (size_t)v * NN + l;

    float e[32], p[32];
    #pragma unroll
    for (int o = 0; o < 32; ++o) {
        e[o] = 2.f * be[o];
        p[o] = 2.f * bp[o];
    }
    #pragma unroll 1
    for (int k = 0; k < 3; ++k) {
        const float* s = (k == 0) ? x : ((k == 1) ? g1 : g2);
        float sc = (k == 0) ? 2.f : 1.f;
        #pragma unroll 1
        for (int c4 = 0; c4 < 8; ++c4) {        // 32 channels in chunks of 4
            float h[4];
            #pragma unroll
            for (int j = 0; j < 4; ++j)
                h[j] = s[base + (size_t)(c4*4 + j)*MAT] * sc;
            #pragma unroll
            for (int o = 0; o < 32; ++o) {
                f32x4 we = *(const f32x4*)&We[o*96 + k*32 + c4*4];   // uniform -> SGPR
                f32x4 wp = *(const f32x4*)&Wp[o*96 + k*32 + c4*4];   // uniform -> SGPR
                #pragma unroll
                for (int j = 0; j < 4; ++j) {
                    e[o] = fmaf(we[j], h[j], e[o]);
                    p[o] = fmaf(wp[j], h[j], p[o]);
                }
            }
        }
    }
    int k8 = v0 >> 2, j = v0 & 3;
    #pragma unroll
    for (int o = 0; o < 32; ++o) {
        size_t bo = (size_t)(b*32 + o);
        pool[bo*MAT + (size_t)v*NN + l] = p[o];
        float en = __shfl_down(e[o], 1);        // partner lane = v+1's e[o]
        if (vbit == 0)
            embed_pk[bo*PKSZ + (size_t)(k8*160 + l)*4 + j] = pk2(e[o], en);
    }
}

// ---------------------------------------------------------------------------
// softmax over node dim (read-only input); emits srpk = PK over node-row pairs
// (B-operand of a@s and A-operand of s^T@embed) AND scpk = PK over column
// pairs (A-operand of s@M, was the separate tpack kernel).  Column-pair values
// come from the neighbor lane via shfl (lane parity == l parity since 160 and
// 64 are even; pair never straddles a wave).  fp32 s is never stored.
// ---------------------------------------------------------------------------
__global__ __launch_bounds__(256) void softmax_n(const float* __restrict__ p,
                                                 u32* __restrict__ srpk,
                                                 u32* __restrict__ scpk)
{
    int idx = blockIdx.x * 256 + threadIdx.x;   // 163,840 columns
    int l  = idx % NN;
    int bo = idx / NN;
    const float* col = p + (size_t)bo * MAT + l;
    float m = -1e30f, s = 0.f;
    for (int n = 0; n < NN; ++n) {
        float v  = col[(size_t)n * NN];
        float mn = fmaxf(m, v);
        s = s * __expf(m - mn) + __expf(v - mn);
        m = mn;
    }
    float inv = 1.f / s;
    u32* sp = srpk + (size_t)bo * PKSZ;
    u32* cp = scpk + (size_t)bo * PKSZ;
    int k8c = l >> 3, jc = (l >> 1) & 3;
    bool wlane = ((l & 1) == 0);
    for (int k2 = 0; k2 < 80; ++k2) {
        float s0 = __expf(col[(size_t)(2*k2)   * NN] - m) * inv;
        float s1 = __expf(col[(size_t)(2*k2+1) * NN] - m) * inv;
        sp[(size_t)((k2 >> 2)*160 + l)*4 + (k2 & 3)] = pk2(s0, s1);
        float t0 = __shfl_down(s0, 1);
        float t1 = __shfl_down(s1, 1);
        if (wlane) {
            cp[(size_t)(k8c*160 + 2*k2)*4 + jc]     = pk2(s0, t0);
            cp[(size_t)(k8c*160 + 2*k2 + 1)*4 + jc] = pk2(s1, t1);
        }
    }
}

// ---------------------------------------------------------------------------
extern "C" void kernel_launch(void* const* d_in, const int* in_sizes, int n_in,
                              void* d_out, int out_size, void* d_ws, size_t ws_size,
                              hipStream_t stream)
{
    const float* x  = (const float*)d_in[0];
    const float* a  = (const float*)d_in[1];
    const float* We = (const float*)d_in[2];
    const float* be = (const float*)d_in[3];
    const float* Wp = (const float*)d_in[4];
    const float* bp = (const float*)d_in[5];

    float* part0 = (float*)d_out;          // pool -> x_new
    float* part1 = part0 + BIG;            // G2 -> a_new

    char* ws = (char*)d_ws;
    // persistent small PK mats: 3 x 51200 B
    u32* At12pk = (u32*)(ws + 0);
    u32* Ah12pk = (u32*)(ws + 51200);
    u32* apk    = (u32*)(ws + 102400);
    // big regions
    float* B1      = (float*)(ws + 256000);                 // 104,857,600 B: G1 -> srpk+scpk
    u32*   R3      = (u32*)  (ws + 256000 + 104857600);     //  52,428,800 B: x_pk -> embed_pk
    u32*   R4      = (u32*)  (ws + 256000 + 157286400);     //  52,428,800 B: M_pk
    // total: 209,971,200 B
    // prep-phase temps live inside B1 (dead before first bgemm writes B1)
    float* sums = B1;                       // 320 floats
    float* A1f  = (float*)((char*)B1 + 1536);
    float* A2f  = A1f + MAT;
    float* Ab1f = A2f + MAT;
    float* Ab2f = Ab1f + MAT;
    u32* x_pk     = R3;
    u32* embed_pk = R3;
    u32* srpk = (u32*)B1;
    u32* scpk = (u32*)((char*)B1 + 52428800);
    u32* M_pk = R4;

    // ---- prep (tiny) ----
    prep_sums<<<160, 256, 0, stream>>>(a, sums);
    prep_norm<<<100, 256, 0, stream>>>(a, sums, A1f, A2f);
    prep_mm  <<<200, 256, 0, stream>>>(A1f, A2f, Ab1f, Ab2f);
    prep_pk  <<<38, 256, 0, stream>>>(a, A1f, A2f, Ab1f, Ab2f,
                                      At12pk, Ah12pk, apk);
    cvt_x_pk <<<12800, 256, 0, stream>>>(x, x_pk);

    // ---- hop GEMMs (merged: G1 = (At1+At2)@x, G2 = (Ab1+Ab2)@x) ----
    bgemm16<<<BCN, 256, 0, stream>>>(At12pk, 0, x_pk, B1,    0, (u32*)0);  // G1
    bgemm16<<<BCN, 256, 0, stream>>>(Ah12pk, 0, x_pk, part1, 0, (u32*)0);  // G2

    // ---- channel mix + softmax(+packs fused) ----
    chanmix<<<3200, 256, 0, stream>>>(x, B1, part1, We, be, Wp, bp, embed_pk, part0);
    softmax_n<<<640, 256, 0, stream>>>(part0, srpk, scpk);

    // ---- output GEMMs ----
    // M = a@s (PK-only output)
    bgemm16<<<BCN, 256, 0, stream>>>(apk, 0, srpk, (float*)0, 0, M_pk);
    // x_new = s^T @ embed
    bgemm16<<<BCN, 256, 0, stream>>>(srpk, (long)PKSZ, embed_pk, part0, 0, (u32*)0);
    // a_new = s @ M
    bgemm16<<<BCN, 256, 0, stream>>>(scpk, (long)PKSZ, M_pk, part1, 0, (u32*)0);
}

// Round 3
// 795.798 us; speedup vs baseline: 1.2865x; 1.1063x over previous
//
#include <hip/hip_runtime.h>

#define NN 160
#define MAT (NN*NN)            // 25600
#define BCN 1024               // B*C
#define BIG ((size_t)BCN * MAT)
#define PKSZ 12800             // uints per bc in PK layout: 20 k8-groups * 160 * 4
#define ALPHA 0.05f
#define BETA  0.95f

typedef unsigned int u32;
typedef __attribute__((ext_vector_type(8))) short short8;   // 8 bf16 = 4 VGPRs
typedef __attribute__((ext_vector_type(4))) float f32x4;

// pack two fp32 -> bf16 pair (RNE), lo in low 16, hi in high 16
static __device__ __forceinline__ u32 pk2(float lo, float hi) {
    u32 a = __float_as_uint(lo), b = __float_as_uint(hi);
    a += 0x7fffu + ((a >> 16) & 1u);
    b += 0x7fffu + ((b >> 16) & 1u);
    return (a >> 16) | (b & 0xffff0000u);
}

// ---------------------------------------------------------------------------
// prep_sums: sums[v] = 1/(rowsum_v(a)+1), sums[160+v] = 1/(colsum_v(a)+1)
// ---------------------------------------------------------------------------
__global__ __launch_bounds__(256) void prep_sums(const float* __restrict__ a,
                                                 float* __restrict__ sums)
{
    __shared__ float rbuf[256], cbuf[256];
    int b = blockIdx.x, t = threadIdx.x;
    float r = 0.f, c = 0.f;
    if (t < NN) { r = a[b*NN + t]; c = a[t*NN + b]; }
    rbuf[t] = r; cbuf[t] = c;
    __syncthreads();
    for (int s = 128; s > 0; s >>= 1) {
        if (t < s) { rbuf[t] += rbuf[t+s]; cbuf[t] += cbuf[t+s]; }
        __syncthreads();
    }
    if (t == 0) {
        sums[b]      = 1.f / (rbuf[0] + 1.f);
        sums[NN + b] = 1.f / (cbuf[0] + 1.f);
    }
}

// ---------------------------------------------------------------------------
// prep_norm: A1f[v][w] = (a[v][w]+d)*rs[v]   (rownorm(a+I))
//            A2f[v][w] = (a[w][v]+d)*cs[v]   (rownorm(a^T+I))
// ---------------------------------------------------------------------------
__global__ __launch_bounds__(256) void prep_norm(
    const float* __restrict__ a, const float* __restrict__ sums,
    float* __restrict__ A1f, float* __restrict__ A2f)
{
    int i = blockIdx.x * 256 + threadIdx.x;   // 25600 exact (100 blocks)
    int v = i / NN, w = i % NN;
    float d = (v == w) ? 1.f : 0.f;
    A1f[i] = (a[v*NN + w] + d) * sums[v];
    A2f[i] = (a[w*NN + v] + d) * sums[NN + v];
}

// ---------------------------------------------------------------------------
// prep_mm: Ab = alpha*I + alpha*beta*A + beta^2 * A@A   for A1f and A2f
// ---------------------------------------------------------------------------
__global__ __launch_bounds__(256) void prep_mm(
    const float* __restrict__ A1f, const float* __restrict__ A2f,
    float* __restrict__ Ab1f, float* __restrict__ Ab2f)
{
    int idx = blockIdx.x * 256 + threadIdx.x;   // 51200 exact (200 blocks)
    int mtx = idx / MAT;
    int i = idx % MAT;
    int v = i / NN, l = i % NN;
    const float* A = mtx ? A2f : A1f;
    float s = 0.f;
    for (int w = 0; w < NN; ++w) s = fmaf(A[v*NN + w], A[w*NN + l], s);
    float d = (v == l) ? ALPHA : 0.f;
    float o = d + ALPHA*BETA*A[i] + BETA*BETA*s;
    (mtx ? Ab2f : Ab1f)[i] = o;
}

// ---------------------------------------------------------------------------
// prep_pk: pack 3 shared A-operand matrices into PK layout.
// G1 = At1@x + At2@x = (At1+At2)@x and G2 = (Ab1+Ab2)@x, so sum BEFORE pack:
// mtx 0: At12 = beta*(A1+A2) + 2*alpha*I ; 1: Ah12 = Ab1+Ab2 ; 2: a
// pk[k8][v][j] = pack(M[v][8k8+2j], M[v][8k8+2j+1])
// ---------------------------------------------------------------------------
__global__ __launch_bounds__(256) void prep_pk(
    const float* __restrict__ a, const float* __restrict__ A1f,
    const float* __restrict__ A2f, const float* __restrict__ Ab1f,
    const float* __restrict__ Ab2f,
    u32* __restrict__ At12pk, u32* __restrict__ Ah12pk, u32* __restrict__ apk)
{
    int idx = blockIdx.x * 256 + threadIdx.x;
    if (idx >= 3 * 3200) return;
    int mtx = idx / 3200;
    int r = idx % 3200;
    int k8 = r / 160, v = r % 160;
    u32 o[4];
    #pragma unroll
    for (int j = 0; j < 4; ++j) {
        int w0 = k8*8 + 2*j;
        float f0, f1;
        if (mtx == 0) {
            f0 = BETA*(A1f[v*NN + w0]     + A2f[v*NN + w0])     + ((v == w0)   ? 2.f*ALPHA : 0.f);
            f1 = BETA*(A1f[v*NN + w0 + 1] + A2f[v*NN + w0 + 1]) + ((v == w0+1) ? 2.f*ALPHA : 0.f);
        } else if (mtx == 1) {
            f0 = Ab1f[v*NN + w0]     + Ab2f[v*NN + w0];
            f1 = Ab1f[v*NN + w0 + 1] + Ab2f[v*NN + w0 + 1];
        } else {
            f0 = a[v*NN + w0];
            f1 = a[v*NN + w0 + 1];
        }
        o[j] = pk2(f0, f1);
    }
    u32* dst = (mtx == 0) ? At12pk : (mtx == 1) ? Ah12pk : apk;
    *(uint4*)&dst[(k8*160 + v)*4] = make_uint4(o[0], o[1], o[2], o[3]);
}

// ---------------------------------------------------------------------------
// cvt_x_pk: x fp32 [bc][v][l] -> PK (contraction dim = v):
//   xpk[bc][k8][l][j] = pack(x[8k8+2j][l], x[8k8+2j+1][l])
// one thread per uint4 (one (bc,k8,l))
// ---------------------------------------------------------------------------
__global__ __launch_bounds__(256) void cvt_x_pk(const float* __restrict__ x,
                                                u32* __restrict__ xpk)
{
    int idx = blockIdx.x * 256 + threadIdx.x;   // 3,276,800 (12800 blocks)
    int l  = idx % NN;
    int k8 = (idx / NN) % 20;
    int bc = idx / 3200;
    const float* xb = x + (size_t)bc * MAT + (size_t)(k8*8) * NN + l;
    u32 o[4];
    #pragma unroll
    for (int j = 0; j < 4; ++j)
        o[j] = pk2(xb[(2*j)*NN], xb[(2*j+1)*NN]);
    *(uint4*)&xpk[(size_t)bc * PKSZ + (size_t)(k8*160 + l)*4] =
        make_uint4(o[0], o[1], o[2], o[3]);
}

// ---------------------------------------------------------------------------
// bgemm16: per-block one bc. C[v][l] = sum_w A(v,w) * Q(w,l), MFMA 16x16x32 bf16.
// A, Q in PK layout. astride=0 for shared A, PKSZ for per-bc A.
// Cf: fp32 output (nullable); cacc: C += result; Cpk: PK output of raw result.
// 4 waves, each an 80x80 quadrant (5x5 tiles of 16x16), K-chunks of 32.
// ---------------------------------------------------------------------------
__global__ __launch_bounds__(256, 2) void bgemm16(
    const u32* __restrict__ Apk, long astride,
    const u32* __restrict__ Qpk,
    float* __restrict__ Cf, int cacc,
    u32* __restrict__ Cpk)
{
    __shared__ u32 As[2560];   // 4 k8-groups x 160 rows x 4 uints = 10240 B
    __shared__ u32 Bs[2560];
    int bc = blockIdx.x;
    int t = threadIdx.x;
    int lane = t & 63, w = t >> 6;
    int q = lane >> 4, ll = lane & 15;
    int v0w = (w >> 1) * 80, l0w = (w & 1) * 80;
    const u32* Ab = Apk + (size_t)bc * (size_t)astride;
    const u32* Qb = Qpk + (size_t)bc * PKSZ;

    f32x4 acc[5][5];
    #pragma unroll
    for (int rt = 0; rt < 5; ++rt)
        #pragma unroll
        for (int ct = 0; ct < 5; ++ct)
            acc[rt][ct] = (f32x4){0.f, 0.f, 0.f, 0.f};

    for (int c = 0; c < 5; ++c) {       // 5 K-chunks of 32
        __syncthreads();
        for (int i = t; i < 640; i += 256) {
            *(uint4*)&As[i*4] = *(const uint4*)&Ab[(size_t)c*2560 + i*4];
            *(uint4*)&Bs[i*4] = *(const uint4*)&Qb[(size_t)c*2560 + i*4];
        }
        __syncthreads();
        short8 af[5], bf[5];
        #pragma unroll
        for (int rt = 0; rt < 5; ++rt)
            af[rt] = *(const short8*)&As[(q*160 + v0w + rt*16 + ll)*4];
        #pragma unroll
        for (int ct = 0; ct < 5; ++ct)
            bf[ct] = *(const short8*)&Bs[(q*160 + l0w + ct*16 + ll)*4];
        #pragma unroll
        for (int rt = 0; rt < 5; ++rt)
            #pragma unroll
            for (int ct = 0; ct < 5; ++ct)
                acc[rt][ct] = __builtin_amdgcn_mfma_f32_16x16x32_bf16(
                    af[rt], bf[ct], acc[rt][ct], 0, 0, 0);
    }

    // epilogue: C/D layout col=lane&15, row=(lane>>4)*4+reg  [m89-verified]
    float* Cb = Cf  ? Cf  + (size_t)bc * MAT  : (float*)0;
    u32*   Pb = Cpk ? Cpk + (size_t)bc * PKSZ : (u32*)0;
    #pragma unroll
    for (int rt = 0; rt < 5; ++rt) {
        int vb = v0w + rt*16 + q*4;       // first of 4 consecutive rows
        #pragma unroll
        for (int ct = 0; ct < 5; ++ct) {
            int l = l0w + ct*16 + ll;
            f32x4 o = acc[rt][ct];
            if (Pb) {                     // PK of raw GEMM result
                int k8 = vb >> 3, j = (vb >> 1) & 3;
                size_t pa = (size_t)(k8*160 + l)*4 + j;
                Pb[pa]     = pk2(o.x, o.y);
                Pb[pa + 1] = pk2(o.z, o.w);
            }
            if (Cb) {
                size_t base = (size_t)vb * NN + l;
                if (cacc) {
                    o.x += Cb[base];
                    o.y += Cb[base + NN];
                    o.z += Cb[base + 2*NN];
                    o.w += Cb[base + 3*NN];
                }
                Cb[base]        = o.x;
                Cb[base + NN]   = o.y;
                Cb[base + 2*NN] = o.z;
                Cb[base + 3*NN] = o.w;
            }
        }
    }
}

// ---------------------------------------------------------------------------
// chanmix v4: one v-row per thread, HALF the output channels per block.
//  - ob derived from blockIdx ONLY -> provably wave-uniform -> We/Wp stay
//    scalar (s_load).  Round-1 derived the split from idx (threadIdx math):
//    compiler couldn't prove uniformity, W fell to vector loads (SGPR 96->32,
//    2.3x regression).  Round-2 kept W scalar but 64 accumulators spilled
//    (VGPR_Count=48: LLVM's memory-bound perf-hint targets 8 waves/SIMD and
//    accepts spills -> WRITE_SIZE 307MB vs 157MB ideal).
//  - 16 e + 16 p accumulators (~50 VGPR live) fits even a 64-VGPR budget;
//    amdgpu_waves_per_eu(2,4) additionally caps the occupancy target at 4
//    waves/EU (measured occupancy was ~48% anyway) so the allocator has
//    up to 128 VGPRs and no incentive to spill.
//  - block pairs (bid & 1) share the same input slab -> second half's
//    x/g1/g2 reads are L2-hot; FETCH should stay ~155MB (round-1's thread-
//    level split doubled it to 307MB).
//  - lane pairing: idx parity == v parity -> embed v-pair via __shfl_down.
// ---------------------------------------------------------------------------
__global__ __launch_bounds__(256) __attribute__((amdgpu_waves_per_eu(2, 4)))
void chanmix(
    const float* __restrict__ x, const float* __restrict__ g1, const float* __restrict__ g2,
    const float* __restrict__ We, const float* __restrict__ be,
    const float* __restrict__ Wp, const float* __restrict__ bp,
    u32* __restrict__ embed_pk, float* __restrict__ pool)
{
    int ob   = (blockIdx.x & 1) * 16;           // channel half: block-uniform
    int bid2 = blockIdx.x >> 1;                 // 3200 data slabs
    int idx  = bid2 * 256 + threadIdx.x;        // 819,200 data positions
    int vbit = idx & 1;
    int t2 = idx >> 1;
    int l  = t2 % NN;
    int v0 = (t2 / NN) % 80;
    int b  = t2 / (NN * 80);
    int v  = 2*v0 + vbit;
    size_t base = (size_t)b * (32*MAT) + (size_t)v * NN + l;

    float e[16], p[16];
    #pragma unroll
    for (int o = 0; o < 16; ++o) {
        e[o] = 2.f * be[ob + o];
        p[o] = 2.f * bp[ob + o];
    }
    #pragma unroll 1
    for (int k = 0; k < 3; ++k) {
        const float* s = (k == 0) ? x : ((k == 1) ? g1 : g2);
        float sc = (k == 0) ? 2.f : 1.f;
        #pragma unroll 1
        for (int c4 = 0; c4 < 8; ++c4) {        // 32 channels in chunks of 4
            float h[4];
            #pragma unroll
            for (int j = 0; j < 4; ++j)
                h[j] = s[base + (size_t)(c4*4 + j)*MAT] * sc;
            #pragma unroll
            for (int o = 0; o < 16; ++o) {
                f32x4 we = *(const f32x4*)&We[(ob + o)*96 + k*32 + c4*4];  // uniform -> SGPR
                f32x4 wp = *(const f32x4*)&Wp[(ob + o)*96 + k*32 + c4*4];  // uniform -> SGPR
                #pragma unroll
                for (int j = 0; j < 4; ++j) {
                    e[o] = fmaf(we[j], h[j], e[o]);
                    p[o] = fmaf(wp[j], h[j], p[o]);
                }
            }
        }
    }
    int k8 = v0 >> 2, j = v0 & 3;
    #pragma unroll
    for (int o = 0; o < 16; ++o) {
        size_t bo = (size_t)(b*32 + ob + o);
        pool[bo*MAT + (size_t)v*NN + l] = p[o];
        float en = __shfl_down(e[o], 1);        // partner lane = v+1's e[o]
        if (vbit == 0)
            embed_pk[bo*PKSZ + (size_t)(k8*160 + l)*4 + j] = pk2(e[o], en);
    }
}

// ---------------------------------------------------------------------------
// softmax over node dim (read-only input); emits srpk = PK over node-row pairs
// (B-operand of a@s and A-operand of s^T@embed) AND scpk = PK over column
// pairs (A-operand of s@M, was the separate tpack kernel).  Column-pair values
// come from the neighbor lane via shfl (lane parity == l parity since 160 and
// 64 are even; pair never straddles a wave).  fp32 s is never stored.
// ---------------------------------------------------------------------------
__global__ __launch_bounds__(256) void softmax_n(const float* __restrict__ p,
                                                 u32* __restrict__ srpk,
                                                 u32* __restrict__ scpk)
{
    int idx = blockIdx.x * 256 + threadIdx.x;   // 163,840 columns
    int l  = idx % NN;
    int bo = idx / NN;
    const float* col = p + (size_t)bo * MAT + l;
    float m = -1e30f, s = 0.f;
    for (int n = 0; n < NN; ++n) {
        float v  = col[(size_t)n * NN];
        float mn = fmaxf(m, v);
        s = s * __expf(m - mn) + __expf(v - mn);
        m = mn;
    }
    float inv = 1.f / s;
    u32* sp = srpk + (size_t)bo * PKSZ;
    u32* cp = scpk + (size_t)bo * PKSZ;
    int k8c = l >> 3, jc = (l >> 1) & 3;
    bool wlane = ((l & 1) == 0);
    for (int k2 = 0; k2 < 80; ++k2) {
        float s0 = __expf(col[(size_t)(2*k2)   * NN] - m) * inv;
        float s1 = __expf(col[(size_t)(2*k2+1) * NN] - m) * inv;
        sp[(size_t)((k2 >> 2)*160 + l)*4 + (k2 & 3)] = pk2(s0, s1);
        float t0 = __shfl_down(s0, 1);
        float t1 = __shfl_down(s1, 1);
        if (wlane) {
            cp[(size_t)(k8c*160 + 2*k2)*4 + jc]     = pk2(s0, t0);
            cp[(size_t)(k8c*160 + 2*k2 + 1)*4 + jc] = pk2(s1, t1);
        }
    }
}

// ---------------------------------------------------------------------------
extern "C" void kernel_launch(void* const* d_in, const int* in_sizes, int n_in,
                              void* d_out, int out_size, void* d_ws, size_t ws_size,
                              hipStream_t stream)
{
    const float* x  = (const float*)d_in[0];
    const float* a  = (const float*)d_in[1];
    const float* We = (const float*)d_in[2];
    const float* be = (const float*)d_in[3];
    const float* Wp = (const float*)d_in[4];
    const float* bp = (const float*)d_in[5];

    float* part0 = (float*)d_out;          // pool -> x_new
    float* part1 = part0 + BIG;            // G2 -> a_new

    char* ws = (char*)d_ws;
    // persistent small PK mats: 3 x 51200 B
    u32* At12pk = (u32*)(ws + 0);
    u32* Ah12pk = (u32*)(ws + 51200);
    u32* apk    = (u32*)(ws + 102400);
    // big regions
    float* B1      = (float*)(ws + 256000);                 // 104,857,600 B: G1 -> srpk+scpk
    u32*   R3      = (u32*)  (ws + 256000 + 104857600);     //  52,428,800 B: x_pk -> embed_pk
    u32*   R4      = (u32*)  (ws + 256000 + 157286400);     //  52,428,800 B: M_pk
    // total: 209,971,200 B
    // prep-phase temps live inside B1 (dead before first bgemm writes B1)
    float* sums = B1;                       // 320 floats
    float* A1f  = (float*)((char*)B1 + 1536);
    float* A2f  = A1f + MAT;
    float* Ab1f = A2f + MAT;
    float* Ab2f = Ab1f + MAT;
    u32* x_pk     = R3;
    u32* embed_pk = R3;
    u32* srpk = (u32*)B1;
    u32* scpk = (u32*)((char*)B1 + 52428800);
    u32* M_pk = R4;

    // ---- prep (tiny) ----
    prep_sums<<<160, 256, 0, stream>>>(a, sums);
    prep_norm<<<100, 256, 0, stream>>>(a, sums, A1f, A2f);
    prep_mm  <<<200, 256, 0, stream>>>(A1f, A2f, Ab1f, Ab2f);
    prep_pk  <<<38, 256, 0, stream>>>(a, A1f, A2f, Ab1f, Ab2f,
                                      At12pk, Ah12pk, apk);
    cvt_x_pk <<<12800, 256, 0, stream>>>(x, x_pk);

    // ---- hop GEMMs (merged: G1 = (At1+At2)@x, G2 = (Ab1+Ab2)@x) ----
    bgemm16<<<BCN, 256, 0, stream>>>(At12pk, 0, x_pk, B1,    0, (u32*)0);  // G1
    bgemm16<<<BCN, 256, 0, stream>>>(Ah12pk, 0, x_pk, part1, 0, (u32*)0);  // G2

    // ---- channel mix + softmax(+packs fused) ----
    chanmix<<<6400, 256, 0, stream>>>(x, B1, part1, We, be, Wp, bp, embed_pk, part0);
    softmax_n<<<640, 256, 0, stream>>>(part0, srpk, scpk);

    // ---- output GEMMs ----
    // M = a@s (PK-only output)
    bgemm16<<<BCN, 256, 0, stream>>>(apk, 0, srpk, (float*)0, 0, M_pk);
    // x_new = s^T @ embed
    bgemm16<<<BCN, 256, 0, stream>>>(srpk, (long)PKSZ, embed_pk, part0, 0, (u32*)0);
    // a_new = s @ M
    bgemm16<<<BCN, 256, 0, stream>>>(scpk, (long)PKSZ, M_pk, part1, 0, (u32*)0);
}